// Round 1
// baseline (1850.791 us; speedup 1.0000x reference)
//
#include <hip/hip_runtime.h>

#define N_NODES 10000
#define E_EDGES 160000
#define IN_DIM  512
#define HID_DIM 512
#define OUT_DIM 256

// ---------------------------------------------------------------------------
// Stage 1: agg[dst] += x[src]  (GIN neighbor sum, eps=-1 kills the self term)
// one block per edge, 128 threads, each thread handles 4 of the 512 dims.
// Also accumulates degree (thread 0).
// ---------------------------------------------------------------------------
__global__ __launch_bounds__(128) void scatter_x_kernel(
    const float* __restrict__ x, const int* __restrict__ src,
    const int* __restrict__ dst, float* __restrict__ agg,
    float* __restrict__ deg) {
  int e = blockIdx.x;
  int t = threadIdx.x;
  int s = src[e], d = dst[e];
  const float4 v = *reinterpret_cast<const float4*>(x + (size_t)s * IN_DIM + t * 4);
  float* ap = agg + (size_t)d * IN_DIM + t * 4;
  atomicAdd(ap + 0, v.x);
  atomicAdd(ap + 1, v.y);
  atomicAdd(ap + 2, v.z);
  atomicAdd(ap + 3, v.w);
  if (t == 0) atomicAdd(deg + d, 1.0f);
}

// deg -> dis = rsqrt(deg + 1)   (+1 = self loop; deg>=1 so where() is moot)
__global__ void dis_kernel(float* __restrict__ deg) {
  int i = blockIdx.x * 256 + threadIdx.x;
  if (i < N_NODES) deg[i] = rsqrtf(deg[i] + 1.0f);
}

// ---------------------------------------------------------------------------
// Generic fp32 tiled GEMM: C[M,Nc] = A[M,K] @ W[K,Nc] (+bias) (+=C if ACC)
// 64x64 block tile, 256 threads, 4x4 per thread, K-tile 16.
// Nc and K must be multiples of 64/16 (true here: 512/256, 512/256).
// ---------------------------------------------------------------------------
template <bool ACC>
__global__ __launch_bounds__(256) void gemm_kernel(
    const float* __restrict__ A, const float* __restrict__ W,
    const float* __restrict__ bias, float* __restrict__ C,
    int M, int K, int Nc) {
  __shared__ float As[16][68];  // [k][m], padded
  __shared__ float Bs[16][68];  // [k][n], padded

  int t = threadIdx.x;
  int tx = t & 15, ty = t >> 4;
  int brow = blockIdx.y * 64, bcol = blockIdx.x * 64;

  float acc[4][4] = {};

  int arow = t >> 2;            // 0..63
  int akg  = (t & 3) * 4;       // 0,4,8,12
  int bkr  = t >> 4;            // 0..15
  int bcg  = (t & 15) * 4;      // 0..60

  for (int k0 = 0; k0 < K; k0 += 16) {
    float4 a;
    if (brow + arow < M)
      a = *reinterpret_cast<const float4*>(A + (size_t)(brow + arow) * K + k0 + akg);
    else
      a = float4{0.f, 0.f, 0.f, 0.f};
    As[akg + 0][arow] = a.x;
    As[akg + 1][arow] = a.y;
    As[akg + 2][arow] = a.z;
    As[akg + 3][arow] = a.w;

    float4 b = *reinterpret_cast<const float4*>(W + (size_t)(k0 + bkr) * Nc + bcol + bcg);
    *reinterpret_cast<float4*>(&Bs[bkr][bcg]) = b;

    __syncthreads();
#pragma unroll
    for (int k = 0; k < 16; ++k) {
      float4 av = *reinterpret_cast<const float4*>(&As[k][ty * 4]);
      float4 bv = *reinterpret_cast<const float4*>(&Bs[k][tx * 4]);
      float aa[4] = {av.x, av.y, av.z, av.w};
      float bb[4] = {bv.x, bv.y, bv.z, bv.w};
#pragma unroll
      for (int i = 0; i < 4; ++i)
#pragma unroll
        for (int j = 0; j < 4; ++j) acc[i][j] += aa[i] * bb[j];
    }
    __syncthreads();
  }

#pragma unroll
  for (int i = 0; i < 4; ++i) {
    int row = brow + ty * 4 + i;
    if (row >= M) continue;
#pragma unroll
    for (int j = 0; j < 4; ++j) {
      int col = bcol + tx * 4 + j;
      float v = acc[i][j];
      if (bias) v += bias[col];
      if (ACC) v += C[(size_t)row * Nc + col];
      C[(size_t)row * Nc + col] = v;
    }
  }
}

// ---------------------------------------------------------------------------
// out_gcn init: out[i] = dis[i]^2 * h[i] + gcn_b   (self-loop term + bias)
// ---------------------------------------------------------------------------
__global__ __launch_bounds__(64) void out_init_kernel(
    const float* __restrict__ h, const float* __restrict__ dis,
    const float* __restrict__ gcn_b, float* __restrict__ out) {
  int i = blockIdx.x;
  int t = threadIdx.x;  // 0..63, 4 dims each
  float di = dis[i];
  float nrm = di * di;
  float4 hv = *reinterpret_cast<const float4*>(h + (size_t)i * OUT_DIM + t * 4);
  float4 bv = *reinterpret_cast<const float4*>(gcn_b + t * 4);
  float4 o{hv.x * nrm + bv.x, hv.y * nrm + bv.y, hv.z * nrm + bv.z, hv.w * nrm + bv.w};
  *reinterpret_cast<float4*>(out + (size_t)i * OUT_DIM + t * 4) = o;
}

// out[dst] += dis[src]*dis[dst] * h[src]
__global__ __launch_bounds__(64) void scatter_h_kernel(
    const float* __restrict__ h, const int* __restrict__ src,
    const int* __restrict__ dst, const float* __restrict__ dis,
    float* __restrict__ out) {
  int e = blockIdx.x;
  int t = threadIdx.x;  // 0..63
  int s = src[e], d = dst[e];
  float nrm = dis[s] * dis[d];
  float4 v = *reinterpret_cast<const float4*>(h + (size_t)s * OUT_DIM + t * 4);
  float* op = out + (size_t)d * OUT_DIM + t * 4;
  atomicAdd(op + 0, v.x * nrm);
  atomicAdd(op + 1, v.y * nrm);
  atomicAdd(op + 2, v.z * nrm);
  atomicAdd(op + 3, v.w * nrm);
}

// ---------------------------------------------------------------------------
// decode: z1 = relu(out @ d1_W + d1_b) @ d2_W + d2_b    one block per node
// ---------------------------------------------------------------------------
__global__ __launch_bounds__(128) void decode_kernel(
    const float* __restrict__ outg, const float* __restrict__ d1_W,
    const float* __restrict__ d1_b, const float* __restrict__ d2_W,
    const float* __restrict__ d2_b, float* __restrict__ z1) {
  __shared__ float row[OUT_DIM];
  __shared__ float s0[128], s1[128];
  int i = blockIdx.x, t = threadIdx.x;
  float2 r = *reinterpret_cast<const float2*>(outg + (size_t)i * OUT_DIM + t * 2);
  row[t * 2] = r.x;
  row[t * 2 + 1] = r.y;
  __syncthreads();
  float acc = d1_b[t];
#pragma unroll 8
  for (int k = 0; k < OUT_DIM; ++k) acc += row[k] * d1_W[k * 128 + t];
  acc = fmaxf(acc, 0.f);
  s0[t] = acc * d2_W[t * 2 + 0];
  s1[t] = acc * d2_W[t * 2 + 1];
  __syncthreads();
  for (int off = 64; off > 0; off >>= 1) {
    if (t < off) {
      s0[t] += s0[t + off];
      s1[t] += s1[t + off];
    }
    __syncthreads();
  }
  if (t == 0) {
    z1[(size_t)i * 2 + 0] = s0[0] + d2_b[0];
    z1[(size_t)i * 2 + 1] = s1[0] + d2_b[1];
  }
}

extern "C" void kernel_launch(void* const* d_in, const int* in_sizes, int n_in,
                              void* d_out, int out_size, void* d_ws, size_t ws_size,
                              hipStream_t stream) {
  const float* x     = (const float*)d_in[0];
  const int*   edge  = (const int*)d_in[1];
  const float* f_W   = (const float*)d_in[2];
  const float* f_b   = (const float*)d_in[3];
  const float* gcn_W = (const float*)d_in[4];
  const float* gcn_b = (const float*)d_in[5];
  const float* d1_W  = (const float*)d_in[6];
  const float* d1_b  = (const float*)d_in[7];
  const float* d2_W  = (const float*)d_in[8];
  const float* d2_b  = (const float*)d_in[9];
  float* out = (float*)d_out;
  float* ws  = (float*)d_ws;

  const int* src = edge;            // edge_index row 0
  const int* dst = edge + E_EDGES;  // edge_index row 1

  // ws layout (floats): [0,512N) agg -> reused as h [0,256N) + out_gcn [256N,512N)
  //                     [512N,1024N) h1;   [1024N,1025N) deg/dis
  float* agg  = ws;
  float* h1   = ws + (size_t)512 * N_NODES;
  float* deg  = ws + (size_t)1024 * N_NODES;
  float* h    = ws;                           // reuse after GEMM1 consumed agg
  float* outg = ws + (size_t)256 * N_NODES;

  hipMemsetAsync(agg, 0, (size_t)512 * N_NODES * sizeof(float), stream);
  hipMemsetAsync(deg, 0, (size_t)N_NODES * sizeof(float), stream);

  scatter_x_kernel<<<E_EDGES, 128, 0, stream>>>(x, src, dst, agg, deg);
  dis_kernel<<<(N_NODES + 255) / 256, 256, 0, stream>>>(deg);

  // h1 = agg @ f_W + f_b          [10000,512]x[512,512]
  gemm_kernel<false><<<dim3(HID_DIM / 64, (N_NODES + 63) / 64), 256, 0, stream>>>(
      agg, f_W, f_b, h1, N_NODES, IN_DIM, HID_DIM);

  // h = x @ gcn_W[0:512] ; h += h1 @ gcn_W[512:1024]   (concat folded)
  gemm_kernel<false><<<dim3(OUT_DIM / 64, (N_NODES + 63) / 64), 256, 0, stream>>>(
      x, gcn_W, nullptr, h, N_NODES, IN_DIM, OUT_DIM);
  gemm_kernel<true><<<dim3(OUT_DIM / 64, (N_NODES + 63) / 64), 256, 0, stream>>>(
      h1, gcn_W + (size_t)IN_DIM * OUT_DIM, nullptr, h, N_NODES, HID_DIM, OUT_DIM);

  // GCN aggregation with symmetric norm + self loops + bias
  out_init_kernel<<<N_NODES, 64, 0, stream>>>(h, deg, gcn_b, outg);
  scatter_h_kernel<<<E_EDGES, 64, 0, stream>>>(h, src, dst, deg, outg);

  // decode MLP
  decode_kernel<<<N_NODES, 128, 0, stream>>>(outg, d1_W, d1_b, d2_W, d2_b, out);
}

// Round 4
// 249.135 us; speedup vs baseline: 7.4289x; 7.4289x over previous
//
#include <hip/hip_runtime.h>

#define N_NODES 10000
#define E_EDGES 160000
#define IN_DIM  512
#define HID_DIM 512
#define OUT_DIM 256

typedef __attribute__((ext_vector_type(8))) short short8;
typedef __attribute__((ext_vector_type(4))) float f32x4;

__device__ __forceinline__ unsigned short f2bh(float f) {
  union { float f; unsigned u; } v; v.f = f;
  return (unsigned short)((v.u + 0x7FFFu + ((v.u >> 16) & 1u)) >> 16);
}
__device__ __forceinline__ float bh2f(unsigned short h) {
  union { unsigned u; float f; } v; v.u = ((unsigned)h) << 16;
  return v.f;
}

// ===========================================================================
// CSR build: count -> exclusive scan (+dis) -> place
// ===========================================================================
__global__ void count_kernel(const int* __restrict__ dst, int* __restrict__ cnt) {
  int e = blockIdx.x * 256 + threadIdx.x;
  if (e < E_EDGES) atomicAdd(&cnt[dst[e]], 1);
}

__global__ __launch_bounds__(1024) void scan_kernel(
    int* __restrict__ cnt, int* __restrict__ row, float* __restrict__ dis) {
  __shared__ int sums[1024];
  const int CH = 10;
  int t = threadIdx.x;
  int c[CH], excl[CH];
  int s = 0;
#pragma unroll
  for (int j = 0; j < CH; ++j) {
    int idx = t * CH + j;
    c[j] = (idx < N_NODES) ? cnt[idx] : 0;
    excl[j] = s;
    s += c[j];
  }
  sums[t] = s;
  __syncthreads();
  for (int off = 1; off < 1024; off <<= 1) {
    int v = (t >= off) ? sums[t - off] : 0;
    __syncthreads();
    if (t >= off) sums[t] += v;
    __syncthreads();
  }
  int base = (t == 0) ? 0 : sums[t - 1];
#pragma unroll
  for (int j = 0; j < CH; ++j) {
    int idx = t * CH + j;
    if (idx < N_NODES) {
      int start = base + excl[j];
      row[idx] = start;
      cnt[idx] = start;  // cursor
      dis[idx] = rsqrtf((float)c[j] + 1.0f);
    }
  }
  if (t == 1023) row[N_NODES] = sums[1023];
}

__global__ void place_kernel(const int* __restrict__ src, const int* __restrict__ dst,
                             int* __restrict__ cursor, int* __restrict__ col) {
  int e = blockIdx.x * 256 + threadIdx.x;
  if (e < E_EDGES) {
    int pos = atomicAdd(&cursor[dst[e]], 1);
    col[pos] = src[e];
  }
}

// ===========================================================================
// GIN aggregation (gather): agg[i] = sum_{s in N(i)} x[s]
// ===========================================================================
__global__ __launch_bounds__(128) void gin_gather_kernel(
    const float* __restrict__ x, const int* __restrict__ row,
    const int* __restrict__ col, float* __restrict__ agg) {
  int i = blockIdx.x, t = threadIdx.x;
  int beg = row[i], end = row[i + 1];
  float4 acc{0.f, 0.f, 0.f, 0.f};
  for (int e = beg; e < end; ++e) {
    int s = col[e];
    float4 v = *reinterpret_cast<const float4*>(x + (size_t)s * IN_DIM + t * 4);
    acc.x += v.x; acc.y += v.y; acc.z += v.z; acc.w += v.w;
  }
  *reinterpret_cast<float4*>(agg + (size_t)i * IN_DIM + t * 4) = acc;
}

// ===========================================================================
// GCN aggregation (gather) fused with self-loop + bias
// ===========================================================================
__global__ __launch_bounds__(64) void gcn_gather_kernel(
    const float* __restrict__ h, const int* __restrict__ row,
    const int* __restrict__ col, const float* __restrict__ dis,
    const float* __restrict__ gcn_b, float* __restrict__ outg) {
  int i = blockIdx.x, t = threadIdx.x;
  int beg = row[i], end = row[i + 1];
  float di = dis[i];
  float4 acc{0.f, 0.f, 0.f, 0.f};
  for (int e = beg; e < end; ++e) {
    int s = col[e];
    float w = dis[s];
    float4 v = *reinterpret_cast<const float4*>(h + (size_t)s * OUT_DIM + t * 4);
    acc.x += w * v.x; acc.y += w * v.y; acc.z += w * v.z; acc.w += w * v.w;
  }
  float4 hv = *reinterpret_cast<const float4*>(h + (size_t)i * OUT_DIM + t * 4);
  float4 bv = *reinterpret_cast<const float4*>(gcn_b + t * 4);
  float self = di * di;
  float4 o{di * acc.x + self * hv.x + bv.x, di * acc.y + self * hv.y + bv.y,
           di * acc.z + self * hv.z + bv.z, di * acc.w + self * hv.w + bv.w};
  *reinterpret_cast<float4*>(outg + (size_t)i * OUT_DIM + t * 4) = o;
}

// ===========================================================================
// Weight transpose + bf16 hi/lo split: W [K][N] fp32 -> Wt_hi/lo [N][K] bf16
// grid (K/256, N); coalesced writes, L2-cached strided reads.
// ===========================================================================
__global__ void convT_kernel(const float* __restrict__ W, unsigned short* __restrict__ hi,
                             unsigned short* __restrict__ lo, int K, int N) {
  int k = blockIdx.x * 256 + threadIdx.x;
  int n = blockIdx.y;
  float a = W[(size_t)k * N + n];
  unsigned short h = f2bh(a);
  hi[(size_t)n * K + k] = h;
  lo[(size_t)n * K + k] = f2bh(a - bh2f(h));
}

// ===========================================================================
// Split-bf16 MFMA GEMM: C[M][N] = A[M][K] @ W + bias, W given as Wt [N][K]
// bf16 hi/lo. A rows come from A0 (k<kSplit, lda=kSplit) else A1 (lda=K-kSplit).
// BM=64 BN=64 BK=32, 256 threads = 4 waves; wave w -> rows [16w,16w+16) x 64 cols.
// LDS tiles stored in fragment-lane order: [(row>>4)*4+g][row&15][8] -> every
// ds_read_b128 is lane-linear (conflict-free by construction).
// ===========================================================================
template <bool BIAS>
__global__ __launch_bounds__(256) void mfma_gemm_kernel(
    const float* __restrict__ A0, const float* __restrict__ A1, int kSplit,
    const unsigned short* __restrict__ Wt_hi, const unsigned short* __restrict__ Wt_lo,
    const float* __restrict__ bias, float* __restrict__ C,
    int M, int K, int N) {
  __shared__ alignas(16) unsigned short Ahi[2048];
  __shared__ alignas(16) unsigned short Alo[2048];
  __shared__ alignas(16) unsigned short Bhi[2048];
  __shared__ alignas(16) unsigned short Blo[2048];

  int t = threadIdx.x;
  int w = t >> 6, l = t & 63;
  int brow = blockIdx.y * 64, bcol = blockIdx.x * 64;

  f32x4 acc0 = {0.f, 0.f, 0.f, 0.f};
  f32x4 acc1 = {0.f, 0.f, 0.f, 0.f};
  f32x4 acc2 = {0.f, 0.f, 0.f, 0.f};
  f32x4 acc3 = {0.f, 0.f, 0.f, 0.f};

  int srow = t >> 2;  // 0..63 (staging row of A / col of Wt)
  int sg   = t & 3;   // k-group (8 bf16 each)
  int soff = ((srow >> 4) * 4 + sg) * 128 + (srow & 15) * 8;  // bf16 units

  for (int k0 = 0; k0 < K; k0 += 32) {
    // ---- stage A (fp32 -> bf16 hi/lo)
    {
      const float* Ap; int kk, lda;
      if (k0 < kSplit) { Ap = A0; kk = k0; lda = kSplit; }
      else             { Ap = A1; kk = k0 - kSplit; lda = K - kSplit; }
      int arow = brow + srow;
      float va[8];
      if (arow < M) {
        const float* p = Ap + (size_t)arow * lda + kk + sg * 8;
        float4 u0 = *reinterpret_cast<const float4*>(p);
        float4 u1 = *reinterpret_cast<const float4*>(p + 4);
        va[0] = u0.x; va[1] = u0.y; va[2] = u0.z; va[3] = u0.w;
        va[4] = u1.x; va[5] = u1.y; va[6] = u1.z; va[7] = u1.w;
      } else {
#pragma unroll
        for (int j = 0; j < 8; ++j) va[j] = 0.f;
      }
      short8 ph, pl;
#pragma unroll
      for (int j = 0; j < 8; ++j) {
        unsigned short h = f2bh(va[j]);
        ph[j] = (short)h;
        pl[j] = (short)f2bh(va[j] - bh2f(h));
      }
      *reinterpret_cast<short8*>(&Ahi[soff]) = ph;
      *reinterpret_cast<short8*>(&Alo[soff]) = pl;
    }
    // ---- stage B (already bf16 hi/lo in Wt, straight copy)
    {
      int col = bcol + srow;  // N multiple of 64 -> no guard
      size_t off = (size_t)col * K + k0 + sg * 8;
      *reinterpret_cast<short8*>(&Bhi[soff]) =
          *reinterpret_cast<const short8*>(Wt_hi + off);
      *reinterpret_cast<short8*>(&Blo[soff]) =
          *reinterpret_cast<const short8*>(Wt_lo + off);
    }
    __syncthreads();

    short8 ah = *reinterpret_cast<const short8*>(&Ahi[w * 512 + l * 8]);
    short8 al = *reinterpret_cast<const short8*>(&Alo[w * 512 + l * 8]);
#define QSTEP(CT, ACCV)                                                        \
  {                                                                            \
    short8 bh = *reinterpret_cast<const short8*>(&Bhi[(CT)*512 + l * 8]);      \
    short8 bl = *reinterpret_cast<const short8*>(&Blo[(CT)*512 + l * 8]);      \
    ACCV = __builtin_amdgcn_mfma_f32_16x16x32_bf16(ah, bh, ACCV, 0, 0, 0);     \
    ACCV = __builtin_amdgcn_mfma_f32_16x16x32_bf16(al, bh, ACCV, 0, 0, 0);     \
    ACCV = __builtin_amdgcn_mfma_f32_16x16x32_bf16(ah, bl, ACCV, 0, 0, 0);     \
  }
    QSTEP(0, acc0)
    QSTEP(1, acc1)
    QSTEP(2, acc2)
    QSTEP(3, acc3)
#undef QSTEP
    __syncthreads();
  }

  // epilogue: C/D layout col=lane&15, row=(lane>>4)*4+reg
  int r0 = brow + w * 16 + (l >> 4) * 4;
  int c0 = bcol + (l & 15);
#define QSTORE(CT, ACCV)                                                       \
  {                                                                            \
    int col = c0 + (CT)*16;                                                    \
    float badd = BIAS ? bias[col] : 0.f;                                       \
    _Pragma("unroll") for (int j = 0; j < 4; ++j) {                            \
      int row = r0 + j;                                                        \
      if (row < M) C[(size_t)row * N + col] = ACCV[j] + badd;                  \
    }                                                                          \
  }
  QSTORE(0, acc0)
  QSTORE(1, acc1)
  QSTORE(2, acc2)
  QSTORE(3, acc3)
#undef QSTORE
}

// ===========================================================================
// fp32 tiled GEMM (fallback tier)
// ===========================================================================
template <bool ACC>
__global__ __launch_bounds__(256) void gemm_kernel(
    const float* __restrict__ A, const float* __restrict__ W,
    const float* __restrict__ bias, float* __restrict__ C,
    int M, int K, int Nc) {
  __shared__ float As[16][68];
  __shared__ float Bs[16][68];
  int t = threadIdx.x;
  int tx = t & 15, ty = t >> 4;
  int brow = blockIdx.y * 64, bcol = blockIdx.x * 64;
  float acc[4][4] = {};
  int arow = t >> 2;
  int akg  = (t & 3) * 4;
  int bkr  = t >> 4;
  int bcg  = (t & 15) * 4;
  for (int k0 = 0; k0 < K; k0 += 16) {
    float4 a;
    if (brow + arow < M)
      a = *reinterpret_cast<const float4*>(A + (size_t)(brow + arow) * K + k0 + akg);
    else
      a = float4{0.f, 0.f, 0.f, 0.f};
    As[akg + 0][arow] = a.x;
    As[akg + 1][arow] = a.y;
    As[akg + 2][arow] = a.z;
    As[akg + 3][arow] = a.w;
    float4 b = *reinterpret_cast<const float4*>(W + (size_t)(k0 + bkr) * Nc + bcol + bcg);
    *reinterpret_cast<float4*>(&Bs[bkr][bcg]) = b;
    __syncthreads();
#pragma unroll
    for (int k = 0; k < 16; ++k) {
      float4 av = *reinterpret_cast<const float4*>(&As[k][ty * 4]);
      float4 bv = *reinterpret_cast<const float4*>(&Bs[k][tx * 4]);
      float aa[4] = {av.x, av.y, av.z, av.w};
      float bb[4] = {bv.x, bv.y, bv.z, bv.w};
#pragma unroll
      for (int i = 0; i < 4; ++i)
#pragma unroll
        for (int j = 0; j < 4; ++j) acc[i][j] += aa[i] * bb[j];
    }
    __syncthreads();
  }
#pragma unroll
  for (int i = 0; i < 4; ++i) {
    int row = brow + ty * 4 + i;
    if (row >= M) continue;
#pragma unroll
    for (int j = 0; j < 4; ++j) {
      int col = bcol + tx * 4 + j;
      float v = acc[i][j];
      if (bias) v += bias[col];
      if (ACC) v += C[(size_t)row * Nc + col];
      C[(size_t)row * Nc + col] = v;
    }
  }
}

// ===========================================================================
// decode MLP
// ===========================================================================
__global__ __launch_bounds__(128) void decode_kernel(
    const float* __restrict__ outg, const float* __restrict__ d1_W,
    const float* __restrict__ d1_b, const float* __restrict__ d2_W,
    const float* __restrict__ d2_b, float* __restrict__ z1) {
  __shared__ float row[OUT_DIM];
  __shared__ float s0[128], s1[128];
  int i = blockIdx.x, t = threadIdx.x;
  float2 r = *reinterpret_cast<const float2*>(outg + (size_t)i * OUT_DIM + t * 2);
  row[t * 2] = r.x;
  row[t * 2 + 1] = r.y;
  __syncthreads();
  float acc = d1_b[t];
#pragma unroll 8
  for (int k = 0; k < OUT_DIM; ++k) acc += row[k] * d1_W[k * 128 + t];
  acc = fmaxf(acc, 0.f);
  s0[t] = acc * d2_W[t * 2 + 0];
  s1[t] = acc * d2_W[t * 2 + 1];
  __syncthreads();
  for (int off = 64; off > 0; off >>= 1) {
    if (t < off) {
      s0[t] += s0[t + off];
      s1[t] += s1[t + off];
    }
    __syncthreads();
  }
  if (t == 0) {
    z1[(size_t)i * 2 + 0] = s0[0] + d2_b[0];
    z1[(size_t)i * 2 + 1] = s1[0] + d2_b[1];
  }
}

// ===========================================================================
// Atomic-path fallback kernels (lowest tier)
// ===========================================================================
__global__ __launch_bounds__(128) void scatter_x_kernel(
    const float* __restrict__ x, const int* __restrict__ src,
    const int* __restrict__ dst, float* __restrict__ agg,
    float* __restrict__ deg) {
  int e = blockIdx.x;
  int t = threadIdx.x;
  int s = src[e], d = dst[e];
  const float4 v = *reinterpret_cast<const float4*>(x + (size_t)s * IN_DIM + t * 4);
  float* ap = agg + (size_t)d * IN_DIM + t * 4;
  atomicAdd(ap + 0, v.x);
  atomicAdd(ap + 1, v.y);
  atomicAdd(ap + 2, v.z);
  atomicAdd(ap + 3, v.w);
  if (t == 0) atomicAdd(deg + d, 1.0f);
}

__global__ void dis_kernel(float* __restrict__ deg) {
  int i = blockIdx.x * 256 + threadIdx.x;
  if (i < N_NODES) deg[i] = rsqrtf(deg[i] + 1.0f);
}

__global__ __launch_bounds__(64) void out_init_kernel(
    const float* __restrict__ h, const float* __restrict__ dis,
    const float* __restrict__ gcn_b, float* __restrict__ out) {
  int i = blockIdx.x;
  int t = threadIdx.x;
  float di = dis[i];
  float nrm = di * di;
  float4 hv = *reinterpret_cast<const float4*>(h + (size_t)i * OUT_DIM + t * 4);
  float4 bv = *reinterpret_cast<const float4*>(gcn_b + t * 4);
  float4 o{hv.x * nrm + bv.x, hv.y * nrm + bv.y, hv.z * nrm + bv.z, hv.w * nrm + bv.w};
  *reinterpret_cast<float4*>(out + (size_t)i * OUT_DIM + t * 4) = o;
}

__global__ __launch_bounds__(64) void scatter_h_kernel(
    const float* __restrict__ h, const int* __restrict__ src,
    const int* __restrict__ dst, const float* __restrict__ dis,
    float* __restrict__ out) {
  int e = blockIdx.x;
  int t = threadIdx.x;
  int s = src[e], d = dst[e];
  float nrm = dis[s] * dis[d];
  float4 v = *reinterpret_cast<const float4*>(h + (size_t)s * OUT_DIM + t * 4);
  float* op = out + (size_t)d * OUT_DIM + t * 4;
  atomicAdd(op + 0, v.x * nrm);
  atomicAdd(op + 1, v.y * nrm);
  atomicAdd(op + 2, v.z * nrm);
  atomicAdd(op + 3, v.w * nrm);
}

// ===========================================================================
extern "C" void kernel_launch(void* const* d_in, const int* in_sizes, int n_in,
                              void* d_out, int out_size, void* d_ws, size_t ws_size,
                              hipStream_t stream) {
  const float* x     = (const float*)d_in[0];
  const int*   edge  = (const int*)d_in[1];
  const float* f_W   = (const float*)d_in[2];
  const float* f_b   = (const float*)d_in[3];
  const float* gcn_W = (const float*)d_in[4];
  const float* gcn_b = (const float*)d_in[5];
  const float* d1_W  = (const float*)d_in[6];
  const float* d1_b  = (const float*)d_in[7];
  const float* d2_W  = (const float*)d_in[8];
  const float* d2_b  = (const float*)d_in[9];
  float* out = (float*)d_out;
  float* ws  = (float*)d_ws;

  const int* src = edge;
  const int* dst = edge + E_EDGES;

  // float ws layout: agg [0,512N) -> reused as h [0,256N) + outg [256N,512N)
  //                  h1 [512N,1024N);  dis [1024N,1025N)
  float* agg  = ws;
  float* h1   = ws + (size_t)512 * N_NODES;
  float* dis  = ws + (size_t)1024 * N_NODES;
  float* h    = ws;
  float* outg = ws + (size_t)256 * N_NODES;

  // int CSR region
  int* icount = (int*)(ws + (size_t)1025 * N_NODES);  // N ints
  int* irow   = icount + N_NODES;                     // N+1 ints
  int* icol   = irow + N_NODES + 1;                   // E ints
  size_t csr_needed = (size_t)1025 * N_NODES * sizeof(float) +
                      (size_t)(2 * N_NODES + 1 + E_EDGES) * sizeof(int);

  // bf16 weight region (16B aligned)
  const size_t WELEMS = 512 * 512;  // == 1024*256
  size_t usOff = (csr_needed + 15) & ~(size_t)15;
  unsigned short* fWt_hi = (unsigned short*)((char*)d_ws + usOff);
  unsigned short* fWt_lo = fWt_hi + WELEMS;
  unsigned short* gWt_hi = fWt_lo + WELEMS;
  unsigned short* gWt_lo = gWt_hi + WELEMS;
  size_t mfma_needed = usOff + 4 * WELEMS * sizeof(unsigned short);

  if (ws_size >= csr_needed) {
    // ---- CSR build
    hipMemsetAsync(icount, 0, (size_t)N_NODES * sizeof(int), stream);
    count_kernel<<<(E_EDGES + 255) / 256, 256, 0, stream>>>(dst, icount);
    scan_kernel<<<1, 1024, 0, stream>>>(icount, irow, dis);
    place_kernel<<<(E_EDGES + 255) / 256, 256, 0, stream>>>(src, dst, icount, icol);

    // ---- GIN aggregation (gather, no atomics)
    gin_gather_kernel<<<N_NODES, 128, 0, stream>>>(x, irow, icol, agg);

    if (ws_size >= mfma_needed) {
      // ---- weight transpose + bf16 split (once per call, cheap)
      convT_kernel<<<dim3(IN_DIM / 256, HID_DIM), 256, 0, stream>>>(
          f_W, fWt_hi, fWt_lo, IN_DIM, HID_DIM);
      convT_kernel<<<dim3((IN_DIM + HID_DIM) / 256, OUT_DIM), 256, 0, stream>>>(
          gcn_W, gWt_hi, gWt_lo, IN_DIM + HID_DIM, OUT_DIM);

      // ---- h1 = agg @ f_W + f_b      (MFMA split-bf16)
      mfma_gemm_kernel<true><<<dim3(HID_DIM / 64, (N_NODES + 63) / 64), 256, 0, stream>>>(
          agg, agg, IN_DIM, fWt_hi, fWt_lo, f_b, h1, N_NODES, IN_DIM, HID_DIM);

      // ---- h = [x | h1] @ gcn_W      (fused K=1024, no bias)
      mfma_gemm_kernel<false><<<dim3(OUT_DIM / 64, (N_NODES + 63) / 64), 256, 0, stream>>>(
          x, h1, IN_DIM, gWt_hi, gWt_lo, nullptr, h, N_NODES, IN_DIM + HID_DIM, OUT_DIM);
    } else {
      gemm_kernel<false><<<dim3(HID_DIM / 64, (N_NODES + 63) / 64), 256, 0, stream>>>(
          agg, f_W, f_b, h1, N_NODES, IN_DIM, HID_DIM);
      gemm_kernel<false><<<dim3(OUT_DIM / 64, (N_NODES + 63) / 64), 256, 0, stream>>>(
          x, gcn_W, nullptr, h, N_NODES, IN_DIM, OUT_DIM);
      gemm_kernel<true><<<dim3(OUT_DIM / 64, (N_NODES + 63) / 64), 256, 0, stream>>>(
          h1, gcn_W + (size_t)IN_DIM * OUT_DIM, nullptr, h, N_NODES, HID_DIM, OUT_DIM);
    }

    // ---- GCN aggregation (gather, fused self-loop + bias)
    gcn_gather_kernel<<<N_NODES, 64, 0, stream>>>(h, irow, icol, dis, gcn_b, outg);

    // ---- decode
    decode_kernel<<<N_NODES, 128, 0, stream>>>(outg, d1_W, d1_b, d2_W, d2_b, out);
  } else {
    // ---- lowest tier: atomic path
    float* deg = dis;
    hipMemsetAsync(agg, 0, (size_t)512 * N_NODES * sizeof(float), stream);
    hipMemsetAsync(deg, 0, (size_t)N_NODES * sizeof(float), stream);
    scatter_x_kernel<<<E_EDGES, 128, 0, stream>>>(x, src, dst, agg, deg);
    dis_kernel<<<(N_NODES + 255) / 256, 256, 0, stream>>>(deg);
    gemm_kernel<false><<<dim3(HID_DIM / 64, (N_NODES + 63) / 64), 256, 0, stream>>>(
        agg, f_W, f_b, h1, N_NODES, IN_DIM, HID_DIM);
    gemm_kernel<false><<<dim3(OUT_DIM / 64, (N_NODES + 63) / 64), 256, 0, stream>>>(
        x, gcn_W, nullptr, h, N_NODES, IN_DIM, OUT_DIM);
    gemm_kernel<true><<<dim3(OUT_DIM / 64, (N_NODES + 63) / 64), 256, 0, stream>>>(
        h1, gcn_W + (size_t)IN_DIM * OUT_DIM, nullptr, h, N_NODES, HID_DIM, OUT_DIM);
    out_init_kernel<<<N_NODES, 64, 0, stream>>>(h, dis, gcn_b, outg);
    scatter_h_kernel<<<E_EDGES, 64, 0, stream>>>(h, src, dst, dis, outg);
    decode_kernel<<<N_NODES, 128, 0, stream>>>(outg, d1_W, d1_b, d2_W, d2_b, out);
  }
}